// Round 1
// baseline (355.454 us; speedup 1.0000x reference)
//
#include <hip/hip_runtime.h>
#include <hip/hip_fp16.h>
#include <math.h>

// Transformer-XL relative multi-head attention, MI355X. B=2,S=2048,D=512,H=8,dh=64.
// Round-13: r12 pipeline; head-chunk capped at 8 so the raw Ppos tensor stays
//   resident in the 256 MB Infinity Cache between pos_gemm and attn_fused.
//   r12 diagnosis: attn_fused FETCH_SIZE == 156 MB/dispatch == the whole 134 MB
//   Ppos buffer read back from HBM (LLC churned by writing all 16 heads before
//   reading any), so every per-tile vmcnt(0) eats ~900-cycle HBM latency at only
//   4 waves/SIMD -> 75% stall (MfmaUtil 4.4%, VALUBusy 21%, HBM 15.6%).
//   Fix: c<=8 -> 67 MB Ppos working set per chunk, written then immediately
//   re-read while LLC-resident; attn grid stays 1024 blocks = 4 blocks/CU
//   (full occupancy; c=4 would halve waves-in-flight, rejected).
//  1. conv_inputs : x,pos fp32 -> fp16.   2. conv_wt: 5 weights -> fp16 W^T.
//  3. proj_mfma   : QU(+u)/QV(+v), K, Pb [s][d]; VT [d][s]  (fp16 MFMA).
//  4. per head-chunk (<=8): pos_gemm -> raw Ppos fp16 ; attn_fused -> ctx fp16.
//  5. out_mfma    : out(fp32) = ctx @ Wo + bo.

#define S_LEN 2048
#define NH 8
#define DHD 64
#define DM 512
#define NBH 16
#define CHUNK_CAP 8
#define HEAD_ELEMS (S_LEN * DHD)
#define SS ((size_t)S_LEN * (size_t)S_LEN)

// workspace byte offsets
#define BY_QU  0u               // fp16 [16][2048][64]  4 MB
#define BY_QV  4194304u         // fp16 [16][2048][64]  4 MB
#define BY_K   8388608u         // fp16 [16][2048][64]  4 MB
#define BY_VT  12582912u        // fp16 [16][64][2048]  4 MB
#define BY_PB  16777216u        // fp16 [16][2048][64]  4 MB
#define BY_XH  20971520u        // fp16 [2][2048][512]  4 MB
#define BY_PH  25165824u        // fp16 [2][2048][512]  4 MB
#define BY_WT  29360128u        // fp16 [5][512][512] transposed, 2.62 MB
#define BY_CTX 31981568u        // fp16 [2][2048][512]  4 MB
#define BY_PP  36175872u        // fp16 [c][2048][2048] raw Ppos, 8.39 MB/head
#define PP_HEAD_BYTES 8388608u
#define WT_MAT_HALFS 262144u

typedef short v8s __attribute__((ext_vector_type(8)));
typedef float v4f __attribute__((ext_vector_type(4)));

static __device__ __forceinline__ unsigned short f2h(float f) {
    __half h = __float2half(f);
    return *reinterpret_cast<unsigned short*>(&h);
}
static __device__ __forceinline__ float h2f(unsigned short u) {
    __half h = *reinterpret_cast<__half*>(&u);
    return __half2float(h);
}

// ---------------------------------------------------------------------------
// conv_inputs: fp32 -> fp16, 4 els/thread. z: 0 = x, 1 = pos.
// ---------------------------------------------------------------------------
__global__ __launch_bounds__(256)
void conv_inputs(const float* __restrict__ x, const float* __restrict__ pos,
                 char* __restrict__ wsb)
{
    const float* src = blockIdx.z ? pos : x;
    unsigned short* dst = (unsigned short*)(wsb + (blockIdx.z ? BY_PH : BY_XH));
    int i = (blockIdx.x * 256 + threadIdx.x) * 4;
    float4 a = *(const float4*)(src + i);
    ushort4 p;
    p.x = f2h(a.x); p.y = f2h(a.y); p.z = f2h(a.z); p.w = f2h(a.w);
    *(ushort4*)(dst + i) = p;
}

// ---------------------------------------------------------------------------
// conv_wt: WT[m][n][k] = W_m[k][n] fp16. 64x64 LDS tile transpose.
// ---------------------------------------------------------------------------
__global__ __launch_bounds__(256)
void conv_wt(const float* __restrict__ Wq, const float* __restrict__ Wk,
             const float* __restrict__ Wv, const float* __restrict__ Wp,
             const float* __restrict__ Wo, char* __restrict__ wsb)
{
    __shared__ float T[64][65];
    const float* W = (blockIdx.z == 0) ? Wq : (blockIdx.z == 1) ? Wk :
                     (blockIdx.z == 2) ? Wv : (blockIdx.z == 3) ? Wp : Wo;
    unsigned short* WT = (unsigned short*)(wsb + BY_WT) + blockIdx.z * WT_MAT_HALFS;
    const int n0 = blockIdx.x * 64, k0 = blockIdx.y * 64;
    const int t = threadIdx.x;
#pragma unroll
    for (int i = 0; i < 4; ++i) {
        int f = t + i * 256;
        int row = f >> 4, c4 = f & 15;
        *(float4*)&T[row][c4 * 4] = *(const float4*)(W + (size_t)(k0 + row) * 512 + n0 + c4 * 4);
    }
    __syncthreads();
#pragma unroll
    for (int i = 0; i < 4; ++i) {
        int f = t + i * 256;
        int n = f >> 4, k4 = f & 15;
        ushort4 p;
        p.x = f2h(T[k4 * 4 + 0][n]); p.y = f2h(T[k4 * 4 + 1][n]);
        p.z = f2h(T[k4 * 4 + 2][n]); p.w = f2h(T[k4 * 4 + 3][n]);
        *(ushort4*)(WT + (size_t)(n0 + n) * 512 + k0 + k4 * 4) = p;
    }
}

// ---------------------------------------------------------------------------
// proj_mfma: all four projections via fp16 MFMA, no LDS, 4 waves = 2x2 64x64.
// modes 0(Q),1(K),3(P): SWAPPED C[d][s]; mode 2(V): C[s][d] -> VT store.
// ---------------------------------------------------------------------------
__global__ __launch_bounds__(256)
void proj_mfma(const float* __restrict__ bq, const float* __restrict__ bk,
               const float* __restrict__ bvp,
               const float* __restrict__ uvec, const float* __restrict__ vvec,
               char* __restrict__ wsb)
{
    const int t = threadIdx.x;
    const int wave = t >> 6, lane = t & 63;
    const int quad = lane >> 4, l16 = lane & 15;
    const int wm = wave >> 1, wn = wave & 1;
    const int mode = blockIdx.z;
    const unsigned short* xh = (const unsigned short*)(wsb + BY_XH);
    const unsigned short* ph = (const unsigned short*)(wsb + BY_PH);
    const unsigned short* wt = (const unsigned short*)(wsb + BY_WT);

    v4f acc[4][4];
#pragma unroll
    for (int i = 0; i < 4; ++i)
#pragma unroll
        for (int j = 0; j < 4; ++j) acc[i][j] = (v4f){0.f, 0.f, 0.f, 0.f};

    if (mode != 2) {
        const int d0 = blockIdx.y * 128 + wm * 64;
        const int s0 = blockIdx.x * 128 + wn * 64;
        const int mat = (mode == 0) ? 0 : (mode == 1) ? 1 : 3;
        const unsigned short* A = wt + (size_t)mat * WT_MAT_HALFS;   // [d][k]
        const unsigned short* B = (mode == 3) ? ph : xh;             // [s][k]

        for (int kk = 0; kk < 16; ++kk) {
            v8s af[4], bf[4];
#pragma unroll
            for (int i = 0; i < 4; ++i) {
                af[i] = *(const v8s*)(A + (size_t)(d0 + i * 16 + l16) * 512 + kk * 32 + quad * 8);
                bf[i] = *(const v8s*)(B + (size_t)(s0 + i * 16 + l16) * 512 + kk * 32 + quad * 8);
            }
#pragma unroll
            for (int i = 0; i < 4; ++i)
#pragma unroll
                for (int j = 0; j < 4; ++j)
                    acc[i][j] = __builtin_amdgcn_mfma_f32_16x16x32_f16(af[i], bf[j], acc[i][j], 0, 0, 0);
        }

#pragma unroll
        for (int i = 0; i < 4; ++i) {
            int db = d0 + i * 16 + quad * 4;
            int h = db >> 6, dl = db & 63;
            float4 b4 = (mode == 3) ? make_float4(0.f, 0.f, 0.f, 0.f)
                        : (mode == 0) ? *(const float4*)(bq + db)
                                      : *(const float4*)(bk + db);
#pragma unroll
            for (int j = 0; j < 4; ++j) {
                int s = s0 + j * 16 + l16;
                int bb = s >> 11, srow = s & 2047;
                size_t o = ((size_t)(bb * NH + h) * S_LEN + srow) * DHD + dl;
                if (mode == 0) {
                    float4 u4 = *(const float4*)(uvec + db);
                    float4 v4 = *(const float4*)(vvec + db);
                    unsigned short* qu = (unsigned short*)(wsb + BY_QU);
                    unsigned short* qv = (unsigned short*)(wsb + BY_QV);
                    ushort4 pu, pv;
                    pu.x = f2h(acc[i][j][0] + b4.x + u4.x);
                    pu.y = f2h(acc[i][j][1] + b4.y + u4.y);
                    pu.z = f2h(acc[i][j][2] + b4.z + u4.z);
                    pu.w = f2h(acc[i][j][3] + b4.w + u4.w);
                    pv.x = f2h(acc[i][j][0] + b4.x + v4.x);
                    pv.y = f2h(acc[i][j][1] + b4.y + v4.y);
                    pv.z = f2h(acc[i][j][2] + b4.z + v4.z);
                    pv.w = f2h(acc[i][j][3] + b4.w + v4.w);
                    *(ushort4*)(qu + o) = pu;
                    *(ushort4*)(qv + o) = pv;
                } else {
                    unsigned short* dst = (unsigned short*)(wsb + (mode == 1 ? BY_K : BY_PB));
                    ushort4 pk;
                    pk.x = f2h(acc[i][j][0] + b4.x);
                    pk.y = f2h(acc[i][j][1] + b4.y);
                    pk.z = f2h(acc[i][j][2] + b4.z);
                    pk.w = f2h(acc[i][j][3] + b4.w);
                    *(ushort4*)(dst + o) = pk;
                }
            }
        }
    } else {
        const int s0 = blockIdx.x * 128 + wm * 64;
        const int d0 = blockIdx.y * 128 + wn * 64;
        const unsigned short* A = xh;                                 // [s][k]
        const unsigned short* B = wt + (size_t)2 * WT_MAT_HALFS;      // [d][k]

        for (int kk = 0; kk < 16; ++kk) {
            v8s af[4], bf[4];
#pragma unroll
            for (int i = 0; i < 4; ++i) {
                af[i] = *(const v8s*)(A + (size_t)(s0 + i * 16 + l16) * 512 + kk * 32 + quad * 8);
                bf[i] = *(const v8s*)(B + (size_t)(d0 + i * 16 + l16) * 512 + kk * 32 + quad * 8);
            }
#pragma unroll
            for (int i = 0; i < 4; ++i)
#pragma unroll
                for (int j = 0; j < 4; ++j)
                    acc[i][j] = __builtin_amdgcn_mfma_f32_16x16x32_f16(af[i], bf[j], acc[i][j], 0, 0, 0);
        }

        unsigned short* vt = (unsigned short*)(wsb + BY_VT);
#pragma unroll
        for (int j = 0; j < 4; ++j) {
            int d = d0 + j * 16 + l16;
            int h = d >> 6, dl = d & 63;
            float bval = bvp[d];
#pragma unroll
            for (int i = 0; i < 4; ++i) {
                int sb = s0 + i * 16 + quad * 4;
                int bb = sb >> 11, srow = sb & 2047;
                size_t o = ((size_t)(bb * NH + h) * DHD + dl) * S_LEN + srow;
                ushort4 pk;
                pk.x = f2h(acc[i][j][0] + bval);
                pk.y = f2h(acc[i][j][1] + bval);
                pk.z = f2h(acc[i][j][2] + bval);
                pk.w = f2h(acc[i][j][3] + bval);
                *(ushort4*)(vt + o) = pk;
            }
        }
    }
}

// ---------------------------------------------------------------------------
// pos GEMM: raw Ppos[q][j] = qv[q].pb[j], stored plain (r11).
// SWAPPED: C[j][q], lane holds 4 consecutive j at fixed q -> ushort4 stores.
// ---------------------------------------------------------------------------
__global__ __launch_bounds__(256)
void pos_gemm(const unsigned short* __restrict__ qv,
              const unsigned short* __restrict__ pb,
              unsigned short* __restrict__ pp, int head_base)
{
    const int t = threadIdx.x;
    const int wave = t >> 6, lane = t & 63;
    const int quad = lane >> 4, l16 = lane & 15;
    const int wm = wave >> 1, wn = wave & 1;
    const int z = blockIdx.z, g = head_base + z;
    const int m0 = blockIdx.y * 128 + wm * 64;   // j-dim (Pb rows)
    const int n0 = blockIdx.x * 128 + wn * 64;   // q-dim (QV rows)

    const unsigned short* A = pb + (size_t)g * HEAD_ELEMS;   // [j][d]
    const unsigned short* B = qv + (size_t)g * HEAD_ELEMS;   // [q][d]
    unsigned short* out = pp + (size_t)z * SS;

    v8s af[4][2], bf[4][2];
#pragma unroll
    for (int i = 0; i < 4; ++i)
#pragma unroll
        for (int kk = 0; kk < 2; ++kk) {
            af[i][kk] = *(const v8s*)(A + (size_t)(m0 + i * 16 + l16) * DHD + kk * 32 + quad * 8);
            bf[i][kk] = *(const v8s*)(B + (size_t)(n0 + i * 16 + l16) * DHD + kk * 32 + quad * 8);
        }

#pragma unroll
    for (int i = 0; i < 4; ++i)
#pragma unroll
        for (int j = 0; j < 4; ++j) {
            v4f c = (v4f){0.f, 0.f, 0.f, 0.f};
            c = __builtin_amdgcn_mfma_f32_16x16x32_f16(af[i][0], bf[j][0], c, 0, 0, 0);
            c = __builtin_amdgcn_mfma_f32_16x16x32_f16(af[i][1], bf[j][1], c, 0, 0, 0);
            int jb = m0 + i * 16 + quad * 4;
            int qcol = n0 + j * 16 + l16;
            ushort4 pk;
            pk.x = f2h(c[0]); pk.y = f2h(c[1]); pk.z = f2h(c[2]); pk.w = f2h(c[3]);
            *(ushort4*)(out + (size_t)qcol * S_LEN + jb) = pk;
        }
}

// ---------------------------------------------------------------------------
// Flash attention (r8 core) with ASYNC Ppos staging.
// Per wave per k-tile: 5x global_load_lds (width 16) gather each q-row's
// rel-shift window (16B-aligned base, 20 chunks/row of 8 halfs) into a
// wave-private LDS buffer: chunk c of row l16 at byte
//   (c>>2)*1024 + (c&3)*256 + l16*16      (inst j covers chunks j*4+quad).
// Extraction (funnel shifts, identical values to r11) reads buffer-local
// idx = rm + nt*16 + quad*4 where rm = albase&7.
// Single buffer: s_waitcnt vmcnt(0) before extraction; lgkmcnt(0) before
// issuing the next tile's DMA.  LDS 40960 B -> exactly 4 blocks/CU.
// ---------------------------------------------------------------------------
__global__ __launch_bounds__(256, 4)
void attn_fused(const unsigned short* __restrict__ qu,
                const unsigned short* __restrict__ kdat,
                const unsigned short* __restrict__ vtg,
                const unsigned short* __restrict__ pp,
                unsigned short* __restrict__ ctx, int head_base)
{
    __shared__ unsigned short SpAll[4][2304];
    __shared__ float MlAll[4][128];
    __shared__ __align__(16) unsigned short PosB[4][2560];  // 5 KB/wave

    const int t = threadIdx.x;
    const int wave = t >> 6, lane = t & 63;
    const int quad = lane >> 4, l16 = lane & 15;
    const int z = blockIdx.x >> 7, qt = blockIdx.x & 127;
    const int g = head_base + z;
    const int q0 = qt * 16;
    const int q = q0 + l16;

    const unsigned short* QU = qu   + (size_t)g * HEAD_ELEMS;
    const unsigned short* Kg = kdat + (size_t)g * HEAD_ELEMS;
    const unsigned short* Vg = vtg  + (size_t)g * HEAD_ELEMS;
    const unsigned short* Pg = pp   + (size_t)z * SS;
    unsigned short* Sp = &SpAll[wave][0];
    unsigned short* pbuf = &PosB[wave][0];

    const int off = (3 * q + 2) & 3;
    const int sh = off * 16;
    const size_t albase = (size_t)(q + 1) * 2047 - 1 - off;
    const int rm = (int)(albase & 7);                       // {0,4}
    const unsigned short* gdma = Pg + (albase - rm);        // 16B-aligned row base

#define ISSUE_POS(K0)                                                         \
    {                                                                         \
        _Pragma("unroll")                                                     \
        for (int jj = 0; jj < 5; ++jj)                                        \
            __builtin_amdgcn_global_load_lds(                                 \
                (const __attribute__((address_space(1))) unsigned int*)       \
                    (gdma + (K0) + (jj * 4 + quad) * 8),                      \
                (__attribute__((address_space(3))) unsigned int*)             \
                    (pbuf + jj * 512),                                        \
                16, 0, 0);                                                    \
    }

    // issue tile 0 DMA immediately
    ISSUE_POS(wave * 512)

    const v8s bq0 = *(const v8s*)(QU + (size_t)(q0 + l16) * DHD + quad * 8);
    const v8s bq1 = *(const v8s*)(QU + (size_t)(q0 + l16) * DHD + 32 + quad * 8);

    float m_run = -1e30f, l_run = 0.f;
    v4f accv[4];
#pragma unroll
    for (int r = 0; r < 4; ++r) accv[r] = (v4f){0.f, 0.f, 0.f, 0.f};
    const float scale = 0.04419417382415922f;

    for (int kt = 0; kt < 4; ++kt) {
        const int k0 = wave * 512 + kt * 128;

        // QK^T
        v4f sacc[8];
#pragma unroll
        for (int nt = 0; nt < 8; ++nt) {
            v8s a0 = *(const v8s*)(Kg + (size_t)(k0 + nt * 16 + l16) * DHD + quad * 8);
            v8s a1 = *(const v8s*)(Kg + (size_t)(k0 + nt * 16 + l16) * DHD + 32 + quad * 8);
            v4f c = (v4f){0.f, 0.f, 0.f, 0.f};
            c = __builtin_amdgcn_mfma_f32_16x16x32_f16(a0, bq0, c, 0, 0, 0);
            c = __builtin_amdgcn_mfma_f32_16x16x32_f16(a1, bq1, c, 0, 0, 0);
            sacc[nt] = c;
        }

        // DMA for this tile complete
        __builtin_amdgcn_s_waitcnt(0x0f70);   // vmcnt(0)

        // add rel-shifted pos from LDS (funnel-shift extract) + scale; local max
        float tm = -1e30f;
#pragma unroll
        for (int nt = 0; nt < 8; ++nt) {
            int kb = k0 + nt * 16 + quad * 4;
            int idx = rm + nt * 16 + quad * 4;
            int i1 = idx + 4;
            int c0 = idx >> 3, o0 = idx & 7;
            int c1 = i1 >> 3, o1 = i1 & 7;
            uint2 wAv = *(const uint2*)((const char*)pbuf +
                         (c0 >> 2) * 1024 + (c0 & 3) * 256 + l16 * 16 + o0 * 2);
            uint2 wBv = *(const uint2*)((const char*)pbuf +
                         (c1 >> 2) * 1024 + (c1 & 3) * 256 + l16 * 16 + o1 * 2);
            unsigned long long c01 = ((unsigned long long)wAv.y << 32) | wAv.x;
            unsigned long long c12 = ((unsigned long long)wBv.x << 32) | wAv.y;
            unsigned long long c23 = ((unsigned long long)wBv.y << 32) | wBv.x;
            unsigned dA = (unsigned)(c01 >> sh);
            unsigned dB = (unsigned)(c12 >> sh);
            unsigned dC = (unsigned)(c23 >> sh);
            unsigned short lo_[4] = { (unsigned short)(dA >> 16),
                                      (unsigned short)(dB & 0xffff),
                                      (unsigned short)(dB >> 16),
                                      (unsigned short)(dC & 0xffff) };
            unsigned short hi_[4] = { (unsigned short)(dA & 0xffff),
                                      (unsigned short)(dA >> 16),
                                      (unsigned short)(dB & 0xffff),
                                      (unsigned short)(dB >> 16) };
#pragma unroll
            for (int reg = 0; reg < 4; ++reg) {
                int k = kb + reg;
                float pv = (k <= q) ? h2f(lo_[reg])
                         : ((k == q + 1) ? 0.f : h2f(hi_[reg]));
                sacc[nt][reg] = (sacc[nt][reg] + pv) * scale;
                tm = fmaxf(tm, sacc[nt][reg]);
            }
        }

        // extraction reads retired -> safe to refill the single buffer
        __builtin_amdgcn_s_waitcnt(0xc07f);   // lgkmcnt(0)
        if (kt < 3) ISSUE_POS(k0 + 128)

        tm = fmaxf(tm, __shfl_xor(tm, 16));
        tm = fmaxf(tm, __shfl_xor(tm, 32));
        float mn = fmaxf(m_run, tm);
        float al = __expf(m_run - mn);
        float rs = 0.f;
#pragma unroll
        for (int nt = 0; nt < 8; ++nt)
#pragma unroll
            for (int reg = 0; reg < 4; ++reg) {
                sacc[nt][reg] = __expf(sacc[nt][reg] - mn);
                rs += sacc[nt][reg];
            }
        rs += __shfl_xor(rs, 16);
        rs += __shfl_xor(rs, 32);
        l_run = l_run * al + rs;
        m_run = mn;

        float alr[4];
#pragma unroll
        for (int reg = 0; reg < 4; ++reg) alr[reg] = __shfl(al, quad * 4 + reg);
#pragma unroll
        for (int ntd = 0; ntd < 4; ++ntd)
#pragma unroll
            for (int reg = 0; reg < 4; ++reg) accv[ntd][reg] *= alr[reg];

#pragma unroll
        for (int nt = 0; nt < 8; ++nt) {
            ushort4 pk;
            pk.x = f2h(sacc[nt][0]); pk.y = f2h(sacc[nt][1]);
            pk.z = f2h(sacc[nt][2]); pk.w = f2h(sacc[nt][3]);
            *(ushort4*)&Sp[l16 * 136 + nt * 16 + quad * 4] = pk;
        }

#pragma unroll
        for (int c4 = 0; c4 < 4; ++c4) {
            v8s ap = *(const v8s*)&Sp[l16 * 136 + c4 * 32 + quad * 8];
#pragma unroll
            for (int ntd = 0; ntd < 4; ++ntd) {
                v8s bv8 = *(const v8s*)(Vg + (size_t)(ntd * 16 + l16) * S_LEN +
                                        k0 + c4 * 32 + quad * 8);
                accv[ntd] = __builtin_amdgcn_mfma_f32_16x16x32_f16(ap, bv8, accv[ntd], 0, 0, 0);
            }
        }
    }
#undef ISSUE_POS

    MlAll[wave][lane * 2]     = m_run;
    MlAll[wave][lane * 2 + 1] = l_run;
    if (wave != 0) {
        float* accSlot = (float*)&SpAll[wave][0];
#pragma unroll
        for (int ntd = 0; ntd < 4; ++ntd)
#pragma unroll
            for (int reg = 0; reg < 4; ++reg)
                accSlot[lane * 16 + ntd * 4 + reg] = accv[ntd][reg];
    }
    __syncthreads();
    if (wave == 0) {
        const int bb = g >> 3, h = g & 7;
        float ew[4][4], inv[4];
#pragma unroll
        for (int reg = 0; reg < 4; ++reg) {
            int qi = quad * 4 + reg;
            float mw[4], lw[4];
#pragma unroll
            for (int w = 0; w < 4; ++w) {
                mw[w] = MlAll[w][qi * 2];
                lw[w] = MlAll[w][qi * 2 + 1];
            }
            float ms = fmaxf(fmaxf(mw[0], mw[1]), fmaxf(mw[2], mw[3]));
            float lt = 0.f;
#pragma unroll
            for (int w = 0; w < 4; ++w) {
                ew[reg][w] = __expf(mw[w] - ms);
                lt += lw[w] * ew[reg][w];
            }
            inv[reg] = 1.f / lt;
        }
#pragma unroll
        for (int ntd = 0; ntd < 4; ++ntd) {
#pragma unroll
            for (int reg = 0; reg < 4; ++reg) {
                float o = accv[ntd][reg] * ew[reg][0];
#pragma unroll
                for (int w = 1; w < 4; ++w) {
                    const float* slot = (const float*)&SpAll[w][0];
                    o += slot[lane * 16 + ntd * 4 + reg] * ew[reg][w];
                }
                int qq = q0 + quad * 4 + reg;
                ctx[((size_t)(bb * S_LEN + qq)) * DM + h * DHD + ntd * 16 + l16] =
                    f2h(o * inv[reg]);
            }
        }
    }
}

// ---------------------------------------------------------------------------
// out_mfma: out(fp32)[s][n] = ctx(fp16) @ Wo + bo.  SWAPPED: C[n][s] ->
// float4 stores.  grid (32, 4): x = s-tile(128), y = n-tile(128).
// ---------------------------------------------------------------------------
__global__ __launch_bounds__(256)
void out_mfma(const float* __restrict__ bo, const char* __restrict__ wsb,
              float* __restrict__ out)
{
    const int t = threadIdx.x;
    const int wave = t >> 6, lane = t & 63;
    const int quad = lane >> 4, l16 = lane & 15;
    const int wm = wave >> 1, wn = wave & 1;
    const int n0 = blockIdx.y * 128 + wm * 64;
    const int s0 = blockIdx.x * 128 + wn * 64;
    const unsigned short* A = (const unsigned short*)(wsb + BY_WT) + (size_t)4 * WT_MAT_HALFS;
    const unsigned short* B = (const unsigned short*)(wsb + BY_CTX);

    v4f acc[4][4];
#pragma unroll
    for (int i = 0; i < 4; ++i)
#pragma unroll
        for (int j = 0; j < 4; ++j) acc[i][j] = (v4f){0.f, 0.f, 0.f, 0.f};

    for (int kk = 0; kk < 16; ++kk) {
        v8s af[4], bf[4];
#pragma unroll
        for (int i = 0; i < 4; ++i) {
            af[i] = *(const v8s*)(A + (size_t)(n0 + i * 16 + l16) * 512 + kk * 32 + quad * 8);
            bf[i] = *(const v8s*)(B + (size_t)(s0 + i * 16 + l16) * 512 + kk * 32 + quad * 8);
        }
#pragma unroll
        for (int i = 0; i < 4; ++i)
#pragma unroll
            for (int j = 0; j < 4; ++j)
                acc[i][j] = __builtin_amdgcn_mfma_f32_16x16x32_f16(af[i], bf[j], acc[i][j], 0, 0, 0);
    }

#pragma unroll
    for (int i = 0; i < 4; ++i) {
        int nb = n0 + i * 16 + quad * 4;
        float4 b4 = *(const float4*)(bo + nb);
#pragma unroll
        for (int j = 0; j < 4; ++j) {
            int s = s0 + j * 16 + l16;
            *(float4*)(out + (size_t)s * DM + nb) =
                make_float4(acc[i][j][0] + b4.x, acc[i][j][1] + b4.y,
                            acc[i][j][2] + b4.z, acc[i][j][3] + b4.w);
        }
    }
}

// Fallback when ws_size is insufficient: clean mismatch instead of OOB writes.
__global__ void zero_fill(float* __restrict__ p, int n)
{
    int i = blockIdx.x * 256 + threadIdx.x;
    if (i < n) p[i] = 0.f;
}

// ---------------------------------------------------------------------------
extern "C" void kernel_launch(void* const* d_in, const int* in_sizes, int n_in,
                              void* d_out, int out_size, void* d_ws, size_t ws_size,
                              hipStream_t stream)
{
    const float* x   = (const float*)d_in[0];
    const float* pos = (const float*)d_in[1];
    const float* Wq  = (const float*)d_in[2];
    const float* bq  = (const float*)d_in[3];
    const float* Wk  = (const float*)d_in[4];
    const float* bk  = (const float*)d_in[5];
    const float* Wv  = (const float*)d_in[6];
    const float* bv  = (const float*)d_in[7];
    const float* Wp  = (const float*)d_in[8];
    const float* u   = (const float*)d_in[9];
    const float* v   = (const float*)d_in[10];
    const float* Wo  = (const float*)d_in[11];
    const float* bo  = (const float*)d_in[12];
    char* wsb  = (char*)d_ws;
    float* out = (float*)d_out;

    // Workspace guard: need BY_PP + >=1 head of raw Ppos + DMA slack.
    if (ws_size < (size_t)BY_PP + PP_HEAD_BYTES + 4096) {
        zero_fill<<<(out_size + 255) / 256, 256, 0, stream>>>(out, out_size);
        return;
    }

    // 1. dtype prep
    conv_inputs<<<dim3(2048, 1, 2), 256, 0, stream>>>(x, pos, wsb);
    conv_wt<<<dim3(8, 8, 5), 256, 0, stream>>>(Wq, Wk, Wv, Wp, Wo, wsb);

    // 2. projections (fp16 MFMA)
    proj_mfma<<<dim3(32, 4, 4), 256, 0, stream>>>(bq, bk, bv, u, v, wsb);

    // 3. attention in head-chunks.  Chunk capped at CHUNK_CAP=8: the per-chunk
    //    raw Ppos (67 MB) written by pos_gemm stays Infinity-Cache-resident for
    //    attn_fused's gather (r12: c=16 -> 134 MB churned the LLC; attn
    //    FETCH_SIZE showed the full Ppos re-read from HBM at ~900 cy latency).
    //    c=8 also keeps the attn grid at 1024 blocks = exactly 4 blocks/CU.
    //    (DMA slack: windows may overread ~64 B past the last head's Ppos;
    //    stays inside d_ws.)
    int c = (int)((ws_size - 4096 - (size_t)BY_PP) / (size_t)PP_HEAD_BYTES);
    if (c < 1) c = 1;
    if (c > CHUNK_CAP) c = CHUNK_CAP;

    for (int g0 = 0; g0 < NBH; g0 += c) {
        int cc = (NBH - g0 < c) ? (NBH - g0) : c;
        pos_gemm<<<dim3(16, 16, cc), 256, 0, stream>>>(
            (const unsigned short*)(wsb + BY_QV),
            (const unsigned short*)(wsb + BY_PB),
            (unsigned short*)(wsb + BY_PP), g0);
        attn_fused<<<dim3(cc * 128), 256, 0, stream>>>(
            (const unsigned short*)(wsb + BY_QU),
            (const unsigned short*)(wsb + BY_K),
            (const unsigned short*)(wsb + BY_VT),
            (const unsigned short*)(wsb + BY_PP),
            (unsigned short*)(wsb + BY_CTX), g0);
    }

    // 4. output projection (fp16 MFMA, fp32 out)
    out_mfma<<<dim3(32, 4), 256, 0, stream>>>(bo, wsb, out);
}

// Round 2
// 330.645 us; speedup vs baseline: 1.0750x; 1.0750x over previous
//
#include <hip/hip_runtime.h>
#include <hip/hip_fp16.h>
#include <math.h>

// Transformer-XL relative multi-head attention, MI355X. B=2,S=2048,D=512,H=8,dh=64.
// Round-14: PRE-SHIFTED Ppos layout ("Pshift").
//   r13 post-mortem: chunking (c=16 vs c=8) left per-head attn cost and
//   per-head FETCH identical -> LLC-residency theory refuted.  Invariant
//   ~1.2 TB/s effective fetch with MfmaUtil 4%/VALU 20%/HBM 15% points at a
//   request-rate/address-divergence ceiling: every global access here is a
//   16-row-divergent gather (K 128B-stride, V/Ppos 4KB-stride rows), and
//   pos_gemm's 8B-per-4KB-row scattered stores explain its ~85us/67MB.
//   Fix this round: pos_gemm writes the SHIFTED tensor Pshift[q][k] directly
//   (identical fp16 values the funnel extraction reconstructed:
//     k<=q  -> raw[q][2047+k-q],  k>q+1 -> raw[q+1][k-q-2],
//     k==q+1 unwritten garbage, masked to 0 in attn as before).
//   pos_gemm: MFMA tile -> LDS [128][132] bounce -> per-q contiguous run
//   writes (dense 2B-per-lane stores, 2-3 lines/inst vs 16).
//   attn: DMA reads aligned contiguous 256B/row windows: 4 insts (was 5),
//   funnel shifts GONE (extraction ~3x fewer VALU), PosB 5KB->4KB/wave.
//  1. conv_inputs : x,pos fp32 -> fp16.   2. conv_wt: 5 weights -> fp16 W^T.
//  3. proj_mfma   : QU(+u)/QV(+v), K, Pb [s][d]; VT [d][s]  (fp16 MFMA).
//  4. per head-chunk: pos_gemm -> Pshift fp16 ; attn_fused -> ctx fp16.
//  5. out_mfma    : out(fp32) = ctx @ Wo + bo.

#define S_LEN 2048
#define NH 8
#define DHD 64
#define DM 512
#define NBH 16
#define CHUNK_CAP 16
#define HEAD_ELEMS (S_LEN * DHD)
#define SS ((size_t)S_LEN * (size_t)S_LEN)

// workspace byte offsets
#define BY_QU  0u               // fp16 [16][2048][64]  4 MB
#define BY_QV  4194304u         // fp16 [16][2048][64]  4 MB
#define BY_K   8388608u         // fp16 [16][2048][64]  4 MB
#define BY_VT  12582912u        // fp16 [16][64][2048]  4 MB
#define BY_PB  16777216u        // fp16 [16][2048][64]  4 MB
#define BY_XH  20971520u        // fp16 [2][2048][512]  4 MB
#define BY_PH  25165824u        // fp16 [2][2048][512]  4 MB
#define BY_WT  29360128u        // fp16 [5][512][512] transposed, 2.62 MB
#define BY_CTX 31981568u        // fp16 [2][2048][512]  4 MB
#define BY_PP  36175872u        // fp16 [c][2048][2048] SHIFTED Ppos, 8.39 MB/head
#define PP_HEAD_BYTES 8388608u
#define WT_MAT_HALFS 262144u

typedef short v8s __attribute__((ext_vector_type(8)));
typedef float v4f __attribute__((ext_vector_type(4)));

static __device__ __forceinline__ unsigned short f2h(float f) {
    __half h = __float2half(f);
    return *reinterpret_cast<unsigned short*>(&h);
}
static __device__ __forceinline__ float h2f(unsigned short u) {
    __half h = *reinterpret_cast<__half*>(&u);
    return __half2float(h);
}

// ---------------------------------------------------------------------------
// conv_inputs: fp32 -> fp16, 4 els/thread. z: 0 = x, 1 = pos.
// ---------------------------------------------------------------------------
__global__ __launch_bounds__(256)
void conv_inputs(const float* __restrict__ x, const float* __restrict__ pos,
                 char* __restrict__ wsb)
{
    const float* src = blockIdx.z ? pos : x;
    unsigned short* dst = (unsigned short*)(wsb + (blockIdx.z ? BY_PH : BY_XH));
    int i = (blockIdx.x * 256 + threadIdx.x) * 4;
    float4 a = *(const float4*)(src + i);
    ushort4 p;
    p.x = f2h(a.x); p.y = f2h(a.y); p.z = f2h(a.z); p.w = f2h(a.w);
    *(ushort4*)(dst + i) = p;
}

// ---------------------------------------------------------------------------
// conv_wt: WT[m][n][k] = W_m[k][n] fp16. 64x64 LDS tile transpose.
// ---------------------------------------------------------------------------
__global__ __launch_bounds__(256)
void conv_wt(const float* __restrict__ Wq, const float* __restrict__ Wk,
             const float* __restrict__ Wv, const float* __restrict__ Wp,
             const float* __restrict__ Wo, char* __restrict__ wsb)
{
    __shared__ float T[64][65];
    const float* W = (blockIdx.z == 0) ? Wq : (blockIdx.z == 1) ? Wk :
                     (blockIdx.z == 2) ? Wv : (blockIdx.z == 3) ? Wp : Wo;
    unsigned short* WT = (unsigned short*)(wsb + BY_WT) + blockIdx.z * WT_MAT_HALFS;
    const int n0 = blockIdx.x * 64, k0 = blockIdx.y * 64;
    const int t = threadIdx.x;
#pragma unroll
    for (int i = 0; i < 4; ++i) {
        int f = t + i * 256;
        int row = f >> 4, c4 = f & 15;
        *(float4*)&T[row][c4 * 4] = *(const float4*)(W + (size_t)(k0 + row) * 512 + n0 + c4 * 4);
    }
    __syncthreads();
#pragma unroll
    for (int i = 0; i < 4; ++i) {
        int f = t + i * 256;
        int n = f >> 4, k4 = f & 15;
        ushort4 p;
        p.x = f2h(T[k4 * 4 + 0][n]); p.y = f2h(T[k4 * 4 + 1][n]);
        p.z = f2h(T[k4 * 4 + 2][n]); p.w = f2h(T[k4 * 4 + 3][n]);
        *(ushort4*)(WT + (size_t)(n0 + n) * 512 + k0 + k4 * 4) = p;
    }
}

// ---------------------------------------------------------------------------
// proj_mfma: all four projections via fp16 MFMA, no LDS, 4 waves = 2x2 64x64.
// modes 0(Q),1(K),3(P): SWAPPED C[d][s]; mode 2(V): C[s][d] -> VT store.
// ---------------------------------------------------------------------------
__global__ __launch_bounds__(256)
void proj_mfma(const float* __restrict__ bq, const float* __restrict__ bk,
               const float* __restrict__ bvp,
               const float* __restrict__ uvec, const float* __restrict__ vvec,
               char* __restrict__ wsb)
{
    const int t = threadIdx.x;
    const int wave = t >> 6, lane = t & 63;
    const int quad = lane >> 4, l16 = lane & 15;
    const int wm = wave >> 1, wn = wave & 1;
    const int mode = blockIdx.z;
    const unsigned short* xh = (const unsigned short*)(wsb + BY_XH);
    const unsigned short* ph = (const unsigned short*)(wsb + BY_PH);
    const unsigned short* wt = (const unsigned short*)(wsb + BY_WT);

    v4f acc[4][4];
#pragma unroll
    for (int i = 0; i < 4; ++i)
#pragma unroll
        for (int j = 0; j < 4; ++j) acc[i][j] = (v4f){0.f, 0.f, 0.f, 0.f};

    if (mode != 2) {
        const int d0 = blockIdx.y * 128 + wm * 64;
        const int s0 = blockIdx.x * 128 + wn * 64;
        const int mat = (mode == 0) ? 0 : (mode == 1) ? 1 : 3;
        const unsigned short* A = wt + (size_t)mat * WT_MAT_HALFS;   // [d][k]
        const unsigned short* B = (mode == 3) ? ph : xh;             // [s][k]

        for (int kk = 0; kk < 16; ++kk) {
            v8s af[4], bf[4];
#pragma unroll
            for (int i = 0; i < 4; ++i) {
                af[i] = *(const v8s*)(A + (size_t)(d0 + i * 16 + l16) * 512 + kk * 32 + quad * 8);
                bf[i] = *(const v8s*)(B + (size_t)(s0 + i * 16 + l16) * 512 + kk * 32 + quad * 8);
            }
#pragma unroll
            for (int i = 0; i < 4; ++i)
#pragma unroll
                for (int j = 0; j < 4; ++j)
                    acc[i][j] = __builtin_amdgcn_mfma_f32_16x16x32_f16(af[i], bf[j], acc[i][j], 0, 0, 0);
        }

#pragma unroll
        for (int i = 0; i < 4; ++i) {
            int db = d0 + i * 16 + quad * 4;
            int h = db >> 6, dl = db & 63;
            float4 b4 = (mode == 3) ? make_float4(0.f, 0.f, 0.f, 0.f)
                        : (mode == 0) ? *(const float4*)(bq + db)
                                      : *(const float4*)(bk + db);
#pragma unroll
            for (int j = 0; j < 4; ++j) {
                int s = s0 + j * 16 + l16;
                int bb = s >> 11, srow = s & 2047;
                size_t o = ((size_t)(bb * NH + h) * S_LEN + srow) * DHD + dl;
                if (mode == 0) {
                    float4 u4 = *(const float4*)(uvec + db);
                    float4 v4 = *(const float4*)(vvec + db);
                    unsigned short* qu = (unsigned short*)(wsb + BY_QU);
                    unsigned short* qv = (unsigned short*)(wsb + BY_QV);
                    ushort4 pu, pv;
                    pu.x = f2h(acc[i][j][0] + b4.x + u4.x);
                    pu.y = f2h(acc[i][j][1] + b4.y + u4.y);
                    pu.z = f2h(acc[i][j][2] + b4.z + u4.z);
                    pu.w = f2h(acc[i][j][3] + b4.w + u4.w);
                    pv.x = f2h(acc[i][j][0] + b4.x + v4.x);
                    pv.y = f2h(acc[i][j][1] + b4.y + v4.y);
                    pv.z = f2h(acc[i][j][2] + b4.z + v4.z);
                    pv.w = f2h(acc[i][j][3] + b4.w + v4.w);
                    *(ushort4*)(qu + o) = pu;
                    *(ushort4*)(qv + o) = pv;
                } else {
                    unsigned short* dst = (unsigned short*)(wsb + (mode == 1 ? BY_K : BY_PB));
                    ushort4 pk;
                    pk.x = f2h(acc[i][j][0] + b4.x);
                    pk.y = f2h(acc[i][j][1] + b4.y);
                    pk.z = f2h(acc[i][j][2] + b4.z);
                    pk.w = f2h(acc[i][j][3] + b4.w);
                    *(ushort4*)(dst + o) = pk;
                }
            }
        }
    } else {
        const int s0 = blockIdx.x * 128 + wm * 64;
        const int d0 = blockIdx.y * 128 + wn * 64;
        const unsigned short* A = xh;                                 // [s][k]
        const unsigned short* B = wt + (size_t)2 * WT_MAT_HALFS;      // [d][k]

        for (int kk = 0; kk < 16; ++kk) {
            v8s af[4], bf[4];
#pragma unroll
            for (int i = 0; i < 4; ++i) {
                af[i] = *(const v8s*)(A + (size_t)(s0 + i * 16 + l16) * 512 + kk * 32 + quad * 8);
                bf[i] = *(const v8s*)(B + (size_t)(d0 + i * 16 + l16) * 512 + kk * 32 + quad * 8);
            }
#pragma unroll
            for (int i = 0; i < 4; ++i)
#pragma unroll
                for (int j = 0; j < 4; ++j)
                    acc[i][j] = __builtin_amdgcn_mfma_f32_16x16x32_f16(af[i], bf[j], acc[i][j], 0, 0, 0);
        }

        unsigned short* vt = (unsigned short*)(wsb + BY_VT);
#pragma unroll
        for (int j = 0; j < 4; ++j) {
            int d = d0 + j * 16 + l16;
            int h = d >> 6, dl = d & 63;
            float bval = bvp[d];
#pragma unroll
            for (int i = 0; i < 4; ++i) {
                int sb = s0 + i * 16 + quad * 4;
                int bb = sb >> 11, srow = sb & 2047;
                size_t o = ((size_t)(bb * NH + h) * DHD + dl) * S_LEN + srow;
                ushort4 pk;
                pk.x = f2h(acc[i][j][0] + bval);
                pk.y = f2h(acc[i][j][1] + bval);
                pk.z = f2h(acc[i][j][2] + bval);
                pk.w = f2h(acc[i][j][3] + bval);
                *(ushort4*)(vt + o) = pk;
            }
        }
    }
}

// ---------------------------------------------------------------------------
// pos GEMM -> SHIFTED store (Round-14).
// MFMA computes raw[j][q] 128x128 tile; bounce through LDS T[q][j]; repack
// writes Pshift[q][k]:
//   raw[r][j]:  j >= 2047-r -> Pshift[r  ][j-2047+r]   (the k<=q values)
//               j <  2047-r -> Pshift[r-1][j+r+1]      (the k>q+1 values)
//   (r==0, j<2047 values are discarded; Pshift[q][q+1] left unwritten ->
//    masked to 0 in attn, as the funnel path did.)
// Store pattern: per target row, 64 lanes x 2B dense contiguous runs
// (2-3 lines/inst) instead of 16-row-divergent 8B scatters.
// ---------------------------------------------------------------------------
__global__ __launch_bounds__(256)
void pos_gemm(const unsigned short* __restrict__ qv,
              const unsigned short* __restrict__ pb,
              unsigned short* __restrict__ pp, int head_base)
{
    __shared__ unsigned short T[128][132];   // [q_local][j_local], pad->no conflicts
    const int t = threadIdx.x;
    const int wave = t >> 6, lane = t & 63;
    const int quad = lane >> 4, l16 = lane & 15;
    const int wm = wave >> 1, wn = wave & 1;
    const int z = blockIdx.z, g = head_base + z;
    const int m0 = blockIdx.y * 128;             // j-block base
    const int n0 = blockIdx.x * 128;             // q-block base
    const int m0w = m0 + wm * 64;                // wave j-subtile
    const int n0w = n0 + wn * 64;                // wave q-subtile

    const unsigned short* A = pb + (size_t)g * HEAD_ELEMS;   // [j][d]
    const unsigned short* B = qv + (size_t)g * HEAD_ELEMS;   // [q][d]
    unsigned short* out = pp + (size_t)z * SS;               // Pshift [q][k]

    v8s af[4][2], bf[4][2];
#pragma unroll
    for (int i = 0; i < 4; ++i)
#pragma unroll
        for (int kk = 0; kk < 2; ++kk) {
            af[i][kk] = *(const v8s*)(A + (size_t)(m0w + i * 16 + l16) * DHD + kk * 32 + quad * 8);
            bf[i][kk] = *(const v8s*)(B + (size_t)(n0w + i * 16 + l16) * DHD + kk * 32 + quad * 8);
        }

#pragma unroll
    for (int i = 0; i < 4; ++i)
#pragma unroll
        for (int j = 0; j < 4; ++j) {
            v4f c = (v4f){0.f, 0.f, 0.f, 0.f};
            c = __builtin_amdgcn_mfma_f32_16x16x32_f16(af[i][0], bf[j][0], c, 0, 0, 0);
            c = __builtin_amdgcn_mfma_f32_16x16x32_f16(af[i][1], bf[j][1], c, 0, 0, 0);
            // lane holds raw[j_glob = m0w+i*16+quad*4+reg][q_glob = n0w+j*16+l16]
            int jl = wm * 64 + i * 16 + quad * 4;    // j_local (mult of 4)
            int ql = wn * 64 + j * 16 + l16;         // q_local
            ushort4 pk;
            pk.x = f2h(c[0]); pk.y = f2h(c[1]); pk.z = f2h(c[2]); pk.w = f2h(c[3]);
            *(ushort4*)&T[ql][jl] = pk;              // 8B-aligned (stride 264B)
        }

    __syncthreads();

    // repack: each wave owns 32 q_locals; 64 lanes cover 128 j's as two
    // dense 64-half passes (e=0: j_local=lane, e=1: j_local=lane+64).
#pragma unroll 4
    for (int m = 0; m < 32; ++m) {
        int ql = wave * 32 + m;
        int q = n0 + ql;
        int jm = 2047 - q - m0;   // j_local < jm -> row q-1 branch
#pragma unroll
        for (int e = 0; e < 2; ++e) {
            int jl = lane + e * 64;
            unsigned short hv = T[ql][jl];
            if (jl < jm) {
                if (q > 0)
                    out[(size_t)(q - 1) * S_LEN + (m0 + jl + q + 1)] = hv;
            } else {
                out[(size_t)q * S_LEN + (m0 + jl - 2047 + q)] = hv;
            }
        }
    }
}

// ---------------------------------------------------------------------------
// Flash attention (r8 core) with ASYNC pre-shifted Ppos staging (Round-14).
// Per wave per k-tile: 4x global_load_lds (width 16) load each q-row's
// CONTIGUOUS ALIGNED Pshift[q][k0..k0+128) window into the wave-private LDS
// buffer: chunk c (16B) of row l16 at byte (c>>2)*1024 + (c&3)*256 + l16*16
// (inst jj covers chunks jj*4+quad).  Extraction is now a single aligned
// uint2 read per nt -- no funnel shifts; k==q+1 masked to 0 (that Pshift
// slot is intentionally unwritten).
// Single buffer: s_waitcnt vmcnt(0) before extraction; lgkmcnt(0) before
// issuing the next tile's DMA.  LDS 36864 B -> 4 blocks/CU.
// ---------------------------------------------------------------------------
__global__ __launch_bounds__(256, 4)
void attn_fused(const unsigned short* __restrict__ qu,
                const unsigned short* __restrict__ kdat,
                const unsigned short* __restrict__ vtg,
                const unsigned short* __restrict__ pp,
                unsigned short* __restrict__ ctx, int head_base)
{
    __shared__ unsigned short SpAll[4][2304];
    __shared__ float MlAll[4][128];
    __shared__ __align__(16) unsigned short PosB[4][2048];  // 4 KB/wave

    const int t = threadIdx.x;
    const int wave = t >> 6, lane = t & 63;
    const int quad = lane >> 4, l16 = lane & 15;
    const int z = blockIdx.x >> 7, qt = blockIdx.x & 127;
    const int g = head_base + z;
    const int q0 = qt * 16;
    const int q = q0 + l16;

    const unsigned short* QU = qu   + (size_t)g * HEAD_ELEMS;
    const unsigned short* Kg = kdat + (size_t)g * HEAD_ELEMS;
    const unsigned short* Vg = vtg  + (size_t)g * HEAD_ELEMS;
    const unsigned short* Pg = pp   + (size_t)z * SS;
    unsigned short* Sp = &SpAll[wave][0];
    unsigned short* pbuf = &PosB[wave][0];

    const unsigned short* gdma = Pg + (size_t)q * S_LEN;    // row base, 4KB-aligned

#define ISSUE_POS(K0)                                                         \
    {                                                                         \
        _Pragma("unroll")                                                     \
        for (int jj = 0; jj < 4; ++jj)                                        \
            __builtin_amdgcn_global_load_lds(                                 \
                (const __attribute__((address_space(1))) unsigned int*)       \
                    (gdma + (K0) + (jj * 4 + quad) * 8),                      \
                (__attribute__((address_space(3))) unsigned int*)             \
                    (pbuf + jj * 512),                                        \
                16, 0, 0);                                                    \
    }

    // issue tile 0 DMA immediately
    ISSUE_POS(wave * 512)

    const v8s bq0 = *(const v8s*)(QU + (size_t)(q0 + l16) * DHD + quad * 8);
    const v8s bq1 = *(const v8s*)(QU + (size_t)(q0 + l16) * DHD + 32 + quad * 8);

    float m_run = -1e30f, l_run = 0.f;
    v4f accv[4];
#pragma unroll
    for (int r = 0; r < 4; ++r) accv[r] = (v4f){0.f, 0.f, 0.f, 0.f};
    const float scale = 0.04419417382415922f;

    for (int kt = 0; kt < 4; ++kt) {
        const int k0 = wave * 512 + kt * 128;

        // QK^T
        v4f sacc[8];
#pragma unroll
        for (int nt = 0; nt < 8; ++nt) {
            v8s a0 = *(const v8s*)(Kg + (size_t)(k0 + nt * 16 + l16) * DHD + quad * 8);
            v8s a1 = *(const v8s*)(Kg + (size_t)(k0 + nt * 16 + l16) * DHD + 32 + quad * 8);
            v4f c = (v4f){0.f, 0.f, 0.f, 0.f};
            c = __builtin_amdgcn_mfma_f32_16x16x32_f16(a0, bq0, c, 0, 0, 0);
            c = __builtin_amdgcn_mfma_f32_16x16x32_f16(a1, bq1, c, 0, 0, 0);
            sacc[nt] = c;
        }

        // DMA for this tile complete
        __builtin_amdgcn_s_waitcnt(0x0f70);   // vmcnt(0)

        // add pre-shifted pos from LDS (aligned uint2 per nt) + scale; local max
        float tm = -1e30f;
#pragma unroll
        for (int nt = 0; nt < 8; ++nt) {
            int kb = k0 + nt * 16 + quad * 4;
            int cc = nt * 2 + (quad >> 1);
            uint2 w = *(const uint2*)((const char*)pbuf +
                         (cc >> 2) * 1024 + (cc & 3) * 256 + l16 * 16 + (quad & 1) * 8);
            unsigned short h_[4] = { (unsigned short)(w.x & 0xffff),
                                     (unsigned short)(w.x >> 16),
                                     (unsigned short)(w.y & 0xffff),
                                     (unsigned short)(w.y >> 16) };
#pragma unroll
            for (int reg = 0; reg < 4; ++reg) {
                int k = kb + reg;
                float pv = (k == q + 1) ? 0.f : h2f(h_[reg]);
                sacc[nt][reg] = (sacc[nt][reg] + pv) * scale;
                tm = fmaxf(tm, sacc[nt][reg]);
            }
        }

        // extraction reads retired -> safe to refill the single buffer
        __builtin_amdgcn_s_waitcnt(0xc07f);   // lgkmcnt(0)
        if (kt < 3) ISSUE_POS(k0 + 128)

        tm = fmaxf(tm, __shfl_xor(tm, 16));
        tm = fmaxf(tm, __shfl_xor(tm, 32));
        float mn = fmaxf(m_run, tm);
        float al = __expf(m_run - mn);
        float rs = 0.f;
#pragma unroll
        for (int nt = 0; nt < 8; ++nt)
#pragma unroll
            for (int reg = 0; reg < 4; ++reg) {
                sacc[nt][reg] = __expf(sacc[nt][reg] - mn);
                rs += sacc[nt][reg];
            }
        rs += __shfl_xor(rs, 16);
        rs += __shfl_xor(rs, 32);
        l_run = l_run * al + rs;
        m_run = mn;

        float alr[4];
#pragma unroll
        for (int reg = 0; reg < 4; ++reg) alr[reg] = __shfl(al, quad * 4 + reg);
#pragma unroll
        for (int ntd = 0; ntd < 4; ++ntd)
#pragma unroll
            for (int reg = 0; reg < 4; ++reg) accv[ntd][reg] *= alr[reg];

#pragma unroll
        for (int nt = 0; nt < 8; ++nt) {
            ushort4 pk;
            pk.x = f2h(sacc[nt][0]); pk.y = f2h(sacc[nt][1]);
            pk.z = f2h(sacc[nt][2]); pk.w = f2h(sacc[nt][3]);
            *(ushort4*)&Sp[l16 * 136 + nt * 16 + quad * 4] = pk;
        }

#pragma unroll
        for (int c4 = 0; c4 < 4; ++c4) {
            v8s ap = *(const v8s*)&Sp[l16 * 136 + c4 * 32 + quad * 8];
#pragma unroll
            for (int ntd = 0; ntd < 4; ++ntd) {
                v8s bv8 = *(const v8s*)(Vg + (size_t)(ntd * 16 + l16) * S_LEN +
                                        k0 + c4 * 32 + quad * 8);
                accv[ntd] = __builtin_amdgcn_mfma_f32_16x16x32_f16(ap, bv8, accv[ntd], 0, 0, 0);
            }
        }
    }
#undef ISSUE_POS

    MlAll[wave][lane * 2]     = m_run;
    MlAll[wave][lane * 2 + 1] = l_run;
    if (wave != 0) {
        float* accSlot = (float*)&SpAll[wave][0];
#pragma unroll
        for (int ntd = 0; ntd < 4; ++ntd)
#pragma unroll
            for (int reg = 0; reg < 4; ++reg)
                accSlot[lane * 16 + ntd * 4 + reg] = accv[ntd][reg];
    }
    __syncthreads();
    if (wave == 0) {
        const int bb = g >> 3, h = g & 7;
        float ew[4][4], inv[4];
#pragma unroll
        for (int reg = 0; reg < 4; ++reg) {
            int qi = quad * 4 + reg;
            float mw[4], lw[4];
#pragma unroll
            for (int w = 0; w < 4; ++w) {
                mw[w] = MlAll[w][qi * 2];
                lw[w] = MlAll[w][qi * 2 + 1];
            }
            float ms = fmaxf(fmaxf(mw[0], mw[1]), fmaxf(mw[2], mw[3]));
            float lt = 0.f;
#pragma unroll
            for (int w = 0; w < 4; ++w) {
                ew[reg][w] = __expf(mw[w] - ms);
                lt += lw[w] * ew[reg][w];
            }
            inv[reg] = 1.f / lt;
        }
#pragma unroll
        for (int ntd = 0; ntd < 4; ++ntd) {
#pragma unroll
            for (int reg = 0; reg < 4; ++reg) {
                float o = accv[ntd][reg] * ew[reg][0];
#pragma unroll
                for (int w = 1; w < 4; ++w) {
                    const float* slot = (const float*)&SpAll[w][0];
                    o += slot[lane * 16 + ntd * 4 + reg] * ew[reg][w];
                }
                int qq = q0 + quad * 4 + reg;
                ctx[((size_t)(bb * S_LEN + qq)) * DM + h * DHD + ntd * 16 + l16] =
                    f2h(o * inv[reg]);
            }
        }
    }
}

// ---------------------------------------------------------------------------
// out_mfma: out(fp32)[s][n] = ctx(fp16) @ Wo + bo.  SWAPPED: C[n][s] ->
// float4 stores.  grid (32, 4): x = s-tile(128), y = n-tile(128).
// ---------------------------------------------------------------------------
__global__ __launch_bounds__(256)
void out_mfma(const float* __restrict__ bo, const char* __restrict__ wsb,
              float* __restrict__ out)
{
    const int t = threadIdx.x;
    const int wave = t >> 6, lane = t & 63;
    const int quad = lane >> 4, l16 = lane & 15;
    const int wm = wave >> 1, wn = wave & 1;
    const int n0 = blockIdx.y * 128 + wm * 64;
    const int s0 = blockIdx.x * 128 + wn * 64;
    const unsigned short* A = (const unsigned short*)(wsb + BY_WT) + (size_t)4 * WT_MAT_HALFS;
    const unsigned short* B = (const unsigned short*)(wsb + BY_CTX);

    v4f acc[4][4];
#pragma unroll
    for (int i = 0; i < 4; ++i)
#pragma unroll
        for (int j = 0; j < 4; ++j) acc[i][j] = (v4f){0.f, 0.f, 0.f, 0.f};

    for (int kk = 0; kk < 16; ++kk) {
        v8s af[4], bf[4];
#pragma unroll
        for (int i = 0; i < 4; ++i) {
            af[i] = *(const v8s*)(A + (size_t)(n0 + i * 16 + l16) * 512 + kk * 32 + quad * 8);
            bf[i] = *(const v8s*)(B + (size_t)(s0 + i * 16 + l16) * 512 + kk * 32 + quad * 8);
        }
#pragma unroll
        for (int i = 0; i < 4; ++i)
#pragma unroll
            for (int j = 0; j < 4; ++j)
                acc[i][j] = __builtin_amdgcn_mfma_f32_16x16x32_f16(af[i], bf[j], acc[i][j], 0, 0, 0);
    }

#pragma unroll
    for (int i = 0; i < 4; ++i) {
        int nb = n0 + i * 16 + quad * 4;
        float4 b4 = *(const float4*)(bo + nb);
#pragma unroll
        for (int j = 0; j < 4; ++j) {
            int s = s0 + j * 16 + l16;
            *(float4*)(out + (size_t)s * DM + nb) =
                make_float4(acc[i][j][0] + b4.x, acc[i][j][1] + b4.y,
                            acc[i][j][2] + b4.z, acc[i][j][3] + b4.w);
        }
    }
}

// Fallback when ws_size is insufficient: clean mismatch instead of OOB writes.
__global__ void zero_fill(float* __restrict__ p, int n)
{
    int i = blockIdx.x * 256 + threadIdx.x;
    if (i < n) p[i] = 0.f;
}

// ---------------------------------------------------------------------------
extern "C" void kernel_launch(void* const* d_in, const int* in_sizes, int n_in,
                              void* d_out, int out_size, void* d_ws, size_t ws_size,
                              hipStream_t stream)
{
    const float* x   = (const float*)d_in[0];
    const float* pos = (const float*)d_in[1];
    const float* Wq  = (const float*)d_in[2];
    const float* bq  = (const float*)d_in[3];
    const float* Wk  = (const float*)d_in[4];
    const float* bk  = (const float*)d_in[5];
    const float* Wv  = (const float*)d_in[6];
    const float* bv  = (const float*)d_in[7];
    const float* Wp  = (const float*)d_in[8];
    const float* u   = (const float*)d_in[9];
    const float* v   = (const float*)d_in[10];
    const float* Wo  = (const float*)d_in[11];
    const float* bo  = (const float*)d_in[12];
    char* wsb  = (char*)d_ws;
    float* out = (float*)d_out;

    // Workspace guard: need BY_PP + >=1 head of Pshift + slack.
    if (ws_size < (size_t)BY_PP + PP_HEAD_BYTES + 4096) {
        zero_fill<<<(out_size + 255) / 256, 256, 0, stream>>>(out, out_size);
        return;
    }

    // 1. dtype prep
    conv_inputs<<<dim3(2048, 1, 2), 256, 0, stream>>>(x, pos, wsb);
    conv_wt<<<dim3(8, 8, 5), 256, 0, stream>>>(Wq, Wk, Wv, Wp, Wo, wsb);

    // 2. projections (fp16 MFMA)
    proj_mfma<<<dim3(32, 4, 4), 256, 0, stream>>>(bq, bk, bv, u, v, wsb);

    // 3. attention in head-chunks sized to workspace (r13 showed chunking has
    //    no cache effect; cap back at 16 to minimize launch count).
    int c = (int)((ws_size - 4096 - (size_t)BY_PP) / (size_t)PP_HEAD_BYTES);
    if (c < 1) c = 1;
    if (c > CHUNK_CAP) c = CHUNK_CAP;

    for (int g0 = 0; g0 < NBH; g0 += c) {
        int cc = (NBH - g0 < c) ? (NBH - g0) : c;
        pos_gemm<<<dim3(16, 16, cc), 256, 0, stream>>>(
            (const unsigned short*)(wsb + BY_QV),
            (const unsigned short*)(wsb + BY_PB),
            (unsigned short*)(wsb + BY_PP), g0);
        attn_fused<<<dim3(cc * 128), 256, 0, stream>>>(
            (const unsigned short*)(wsb + BY_QU),
            (const unsigned short*)(wsb + BY_K),
            (const unsigned short*)(wsb + BY_VT),
            (const unsigned short*)(wsb + BY_PP),
            (unsigned short*)(wsb + BY_CTX), g0);
    }

    // 4. output projection (fp16 MFMA, fp32 out)
    out_mfma<<<dim3(32, 4), 256, 0, stream>>>(bo, wsb, out);
}

// Round 3
// 256.468 us; speedup vs baseline: 1.3860x; 1.2892x over previous
//
#include <hip/hip_runtime.h>
#include <hip/hip_fp16.h>
#include <math.h>

// Transformer-XL relative multi-head attention, MI355X. B=2,S=2048,D=512,H=8,dh=64.
// Round-15: attn_fused rewritten as q-split + cooperative bulk LDS staging.
//   r14 post-mortem: attn invariant at ~142us with NOTHING saturated
//   (MfmaUtil 4.8, VALU 18, HBM 9.4) and ~36k cycles wall per ~3k-cycle
//   wave-tile -> per-wave SERIALIZED memory latency: VGPR=64 forces the
//   compiler to keep <=2 K/V loads in flight, so each of ~24 load->MFMA
//   pairs eats a full L2/LLC round trip (L2 trashed by the 134MB Ppos
//   stream), and 3.4 waves/SIMD can't cover it.  Register prefetch can't
//   fix it (needs ~96 transient VGPRs; r9 showed that trade fails).
//   Fix: block = 64 q-rows (4 waves x 16), all waves march the SAME
//   k-tiles; per tile the block stages K (16KB contiguous), V (16KB) and
//   per-wave Pshift windows with 36 back-to-back global_load_lds (zero
//   VGPR cost, one barrier-drain per tile instead of 24 serial waits).
//   XOR-swizzled global source + linear LDS dest -> conflict-free ds_read
//   fragments.  P->A-fragment via in-register shfl transpose (no Sp LDS):
//   LDS = 48KB -> 2 blocks/CU.  K/V L2 traffic drops 4x (waves share).
//   Epilogue simplifies: each wave owns its q-rows end-to-end.
//  1. conv_inputs : x,pos fp32 -> fp16.   2. conv_wt: 5 weights -> fp16 W^T.
//  3. proj_mfma   : QU(+u)/QV(+v), K, Pb [s][d]; VT [d][s]  (fp16 MFMA).
//  4. per head-chunk: pos_gemm -> Pshift fp16 ; attn_fused -> ctx fp16.
//  5. out_mfma    : out(fp32) = ctx @ Wo + bo.

#define S_LEN 2048
#define NH 8
#define DHD 64
#define DM 512
#define NBH 16
#define CHUNK_CAP 16
#define HEAD_ELEMS (S_LEN * DHD)
#define SS ((size_t)S_LEN * (size_t)S_LEN)

// workspace byte offsets
#define BY_QU  0u               // fp16 [16][2048][64]  4 MB
#define BY_QV  4194304u         // fp16 [16][2048][64]  4 MB
#define BY_K   8388608u         // fp16 [16][2048][64]  4 MB
#define BY_VT  12582912u        // fp16 [16][64][2048]  4 MB
#define BY_PB  16777216u        // fp16 [16][2048][64]  4 MB
#define BY_XH  20971520u        // fp16 [2][2048][512]  4 MB
#define BY_PH  25165824u        // fp16 [2][2048][512]  4 MB
#define BY_WT  29360128u        // fp16 [5][512][512] transposed, 2.62 MB
#define BY_CTX 31981568u        // fp16 [2][2048][512]  4 MB
#define BY_PP  36175872u        // fp16 [c][2048][2048] SHIFTED Ppos, 8.39 MB/head
#define PP_HEAD_BYTES 8388608u
#define WT_MAT_HALFS 262144u

typedef short v8s __attribute__((ext_vector_type(8)));
typedef float v4f __attribute__((ext_vector_type(4)));

static __device__ __forceinline__ unsigned short f2h(float f) {
    __half h = __float2half(f);
    return *reinterpret_cast<unsigned short*>(&h);
}
static __device__ __forceinline__ float h2f(unsigned short u) {
    __half h = *reinterpret_cast<__half*>(&u);
    return __half2float(h);
}
static __device__ __forceinline__ unsigned pkh(float a, float b) {
    return (unsigned)f2h(a) | ((unsigned)f2h(b) << 16);
}

// ---------------------------------------------------------------------------
// conv_inputs: fp32 -> fp16, 4 els/thread. z: 0 = x, 1 = pos.
// ---------------------------------------------------------------------------
__global__ __launch_bounds__(256)
void conv_inputs(const float* __restrict__ x, const float* __restrict__ pos,
                 char* __restrict__ wsb)
{
    const float* src = blockIdx.z ? pos : x;
    unsigned short* dst = (unsigned short*)(wsb + (blockIdx.z ? BY_PH : BY_XH));
    int i = (blockIdx.x * 256 + threadIdx.x) * 4;
    float4 a = *(const float4*)(src + i);
    ushort4 p;
    p.x = f2h(a.x); p.y = f2h(a.y); p.z = f2h(a.z); p.w = f2h(a.w);
    *(ushort4*)(dst + i) = p;
}

// ---------------------------------------------------------------------------
// conv_wt: WT[m][n][k] = W_m[k][n] fp16. 64x64 LDS tile transpose.
// ---------------------------------------------------------------------------
__global__ __launch_bounds__(256)
void conv_wt(const float* __restrict__ Wq, const float* __restrict__ Wk,
             const float* __restrict__ Wv, const float* __restrict__ Wp,
             const float* __restrict__ Wo, char* __restrict__ wsb)
{
    __shared__ float T[64][65];
    const float* W = (blockIdx.z == 0) ? Wq : (blockIdx.z == 1) ? Wk :
                     (blockIdx.z == 2) ? Wv : (blockIdx.z == 3) ? Wp : Wo;
    unsigned short* WT = (unsigned short*)(wsb + BY_WT) + blockIdx.z * WT_MAT_HALFS;
    const int n0 = blockIdx.x * 64, k0 = blockIdx.y * 64;
    const int t = threadIdx.x;
#pragma unroll
    for (int i = 0; i < 4; ++i) {
        int f = t + i * 256;
        int row = f >> 4, c4 = f & 15;
        *(float4*)&T[row][c4 * 4] = *(const float4*)(W + (size_t)(k0 + row) * 512 + n0 + c4 * 4);
    }
    __syncthreads();
#pragma unroll
    for (int i = 0; i < 4; ++i) {
        int f = t + i * 256;
        int n = f >> 4, k4 = f & 15;
        ushort4 p;
        p.x = f2h(T[k4 * 4 + 0][n]); p.y = f2h(T[k4 * 4 + 1][n]);
        p.z = f2h(T[k4 * 4 + 2][n]); p.w = f2h(T[k4 * 4 + 3][n]);
        *(ushort4*)(WT + (size_t)(n0 + n) * 512 + k0 + k4 * 4) = p;
    }
}

// ---------------------------------------------------------------------------
// proj_mfma: all four projections via fp16 MFMA, no LDS, 4 waves = 2x2 64x64.
// modes 0(Q),1(K),3(P): SWAPPED C[d][s]; mode 2(V): C[s][d] -> VT store.
// ---------------------------------------------------------------------------
__global__ __launch_bounds__(256)
void proj_mfma(const float* __restrict__ bq, const float* __restrict__ bk,
               const float* __restrict__ bvp,
               const float* __restrict__ uvec, const float* __restrict__ vvec,
               char* __restrict__ wsb)
{
    const int t = threadIdx.x;
    const int wave = t >> 6, lane = t & 63;
    const int quad = lane >> 4, l16 = lane & 15;
    const int wm = wave >> 1, wn = wave & 1;
    const int mode = blockIdx.z;
    const unsigned short* xh = (const unsigned short*)(wsb + BY_XH);
    const unsigned short* ph = (const unsigned short*)(wsb + BY_PH);
    const unsigned short* wt = (const unsigned short*)(wsb + BY_WT);

    v4f acc[4][4];
#pragma unroll
    for (int i = 0; i < 4; ++i)
#pragma unroll
        for (int j = 0; j < 4; ++j) acc[i][j] = (v4f){0.f, 0.f, 0.f, 0.f};

    if (mode != 2) {
        const int d0 = blockIdx.y * 128 + wm * 64;
        const int s0 = blockIdx.x * 128 + wn * 64;
        const int mat = (mode == 0) ? 0 : (mode == 1) ? 1 : 3;
        const unsigned short* A = wt + (size_t)mat * WT_MAT_HALFS;   // [d][k]
        const unsigned short* B = (mode == 3) ? ph : xh;             // [s][k]

        for (int kk = 0; kk < 16; ++kk) {
            v8s af[4], bf[4];
#pragma unroll
            for (int i = 0; i < 4; ++i) {
                af[i] = *(const v8s*)(A + (size_t)(d0 + i * 16 + l16) * 512 + kk * 32 + quad * 8);
                bf[i] = *(const v8s*)(B + (size_t)(s0 + i * 16 + l16) * 512 + kk * 32 + quad * 8);
            }
#pragma unroll
            for (int i = 0; i < 4; ++i)
#pragma unroll
                for (int j = 0; j < 4; ++j)
                    acc[i][j] = __builtin_amdgcn_mfma_f32_16x16x32_f16(af[i], bf[j], acc[i][j], 0, 0, 0);
        }

#pragma unroll
        for (int i = 0; i < 4; ++i) {
            int db = d0 + i * 16 + quad * 4;
            int h = db >> 6, dl = db & 63;
            float4 b4 = (mode == 3) ? make_float4(0.f, 0.f, 0.f, 0.f)
                        : (mode == 0) ? *(const float4*)(bq + db)
                                      : *(const float4*)(bk + db);
#pragma unroll
            for (int j = 0; j < 4; ++j) {
                int s = s0 + j * 16 + l16;
                int bb = s >> 11, srow = s & 2047;
                size_t o = ((size_t)(bb * NH + h) * S_LEN + srow) * DHD + dl;
                if (mode == 0) {
                    float4 u4 = *(const float4*)(uvec + db);
                    float4 v4 = *(const float4*)(vvec + db);
                    unsigned short* qu = (unsigned short*)(wsb + BY_QU);
                    unsigned short* qv = (unsigned short*)(wsb + BY_QV);
                    ushort4 pu, pv;
                    pu.x = f2h(acc[i][j][0] + b4.x + u4.x);
                    pu.y = f2h(acc[i][j][1] + b4.y + u4.y);
                    pu.z = f2h(acc[i][j][2] + b4.z + u4.z);
                    pu.w = f2h(acc[i][j][3] + b4.w + u4.w);
                    pv.x = f2h(acc[i][j][0] + b4.x + v4.x);
                    pv.y = f2h(acc[i][j][1] + b4.y + v4.y);
                    pv.z = f2h(acc[i][j][2] + b4.z + v4.z);
                    pv.w = f2h(acc[i][j][3] + b4.w + v4.w);
                    *(ushort4*)(qu + o) = pu;
                    *(ushort4*)(qv + o) = pv;
                } else {
                    unsigned short* dst = (unsigned short*)(wsb + (mode == 1 ? BY_K : BY_PB));
                    ushort4 pk;
                    pk.x = f2h(acc[i][j][0] + b4.x);
                    pk.y = f2h(acc[i][j][1] + b4.y);
                    pk.z = f2h(acc[i][j][2] + b4.z);
                    pk.w = f2h(acc[i][j][3] + b4.w);
                    *(ushort4*)(dst + o) = pk;
                }
            }
        }
    } else {
        const int s0 = blockIdx.x * 128 + wm * 64;
        const int d0 = blockIdx.y * 128 + wn * 64;
        const unsigned short* A = xh;                                 // [s][k]
        const unsigned short* B = wt + (size_t)2 * WT_MAT_HALFS;      // [d][k]

        for (int kk = 0; kk < 16; ++kk) {
            v8s af[4], bf[4];
#pragma unroll
            for (int i = 0; i < 4; ++i) {
                af[i] = *(const v8s*)(A + (size_t)(s0 + i * 16 + l16) * 512 + kk * 32 + quad * 8);
                bf[i] = *(const v8s*)(B + (size_t)(d0 + i * 16 + l16) * 512 + kk * 32 + quad * 8);
            }
#pragma unroll
            for (int i = 0; i < 4; ++i)
#pragma unroll
                for (int j = 0; j < 4; ++j)
                    acc[i][j] = __builtin_amdgcn_mfma_f32_16x16x32_f16(af[i], bf[j], acc[i][j], 0, 0, 0);
        }

        unsigned short* vt = (unsigned short*)(wsb + BY_VT);
#pragma unroll
        for (int j = 0; j < 4; ++j) {
            int d = d0 + j * 16 + l16;
            int h = d >> 6, dl = d & 63;
            float bval = bvp[d];
#pragma unroll
            for (int i = 0; i < 4; ++i) {
                int sb = s0 + i * 16 + quad * 4;
                int bb = sb >> 11, srow = sb & 2047;
                size_t o = ((size_t)(bb * NH + h) * DHD + dl) * S_LEN + srow;
                ushort4 pk;
                pk.x = f2h(acc[i][j][0] + bval);
                pk.y = f2h(acc[i][j][1] + bval);
                pk.z = f2h(acc[i][j][2] + bval);
                pk.w = f2h(acc[i][j][3] + bval);
                *(ushort4*)(vt + o) = pk;
            }
        }
    }
}

// ---------------------------------------------------------------------------
// pos GEMM -> SHIFTED store (unchanged from Round-14, verified).
// ---------------------------------------------------------------------------
__global__ __launch_bounds__(256)
void pos_gemm(const unsigned short* __restrict__ qv,
              const unsigned short* __restrict__ pb,
              unsigned short* __restrict__ pp, int head_base)
{
    __shared__ unsigned short T[128][132];   // [q_local][j_local], pad->no conflicts
    const int t = threadIdx.x;
    const int wave = t >> 6, lane = t & 63;
    const int quad = lane >> 4, l16 = lane & 15;
    const int wm = wave >> 1, wn = wave & 1;
    const int z = blockIdx.z, g = head_base + z;
    const int m0 = blockIdx.y * 128;             // j-block base
    const int n0 = blockIdx.x * 128;             // q-block base
    const int m0w = m0 + wm * 64;                // wave j-subtile
    const int n0w = n0 + wn * 64;                // wave q-subtile

    const unsigned short* A = pb + (size_t)g * HEAD_ELEMS;   // [j][d]
    const unsigned short* B = qv + (size_t)g * HEAD_ELEMS;   // [q][d]
    unsigned short* out = pp + (size_t)z * SS;               // Pshift [q][k]

    v8s af[4][2], bf[4][2];
#pragma unroll
    for (int i = 0; i < 4; ++i)
#pragma unroll
        for (int kk = 0; kk < 2; ++kk) {
            af[i][kk] = *(const v8s*)(A + (size_t)(m0w + i * 16 + l16) * DHD + kk * 32 + quad * 8);
            bf[i][kk] = *(const v8s*)(B + (size_t)(n0w + i * 16 + l16) * DHD + kk * 32 + quad * 8);
        }

#pragma unroll
    for (int i = 0; i < 4; ++i)
#pragma unroll
        for (int j = 0; j < 4; ++j) {
            v4f c = (v4f){0.f, 0.f, 0.f, 0.f};
            c = __builtin_amdgcn_mfma_f32_16x16x32_f16(af[i][0], bf[j][0], c, 0, 0, 0);
            c = __builtin_amdgcn_mfma_f32_16x16x32_f16(af[i][1], bf[j][1], c, 0, 0, 0);
            int jl = wm * 64 + i * 16 + quad * 4;    // j_local (mult of 4)
            int ql = wn * 64 + j * 16 + l16;         // q_local
            ushort4 pk;
            pk.x = f2h(c[0]); pk.y = f2h(c[1]); pk.z = f2h(c[2]); pk.w = f2h(c[3]);
            *(ushort4*)&T[ql][jl] = pk;              // 8B-aligned (stride 264B)
        }

    __syncthreads();

#pragma unroll 4
    for (int m = 0; m < 32; ++m) {
        int ql = wave * 32 + m;
        int q = n0 + ql;
        int jm = 2047 - q - m0;   // j_local < jm -> row q-1 branch
#pragma unroll
        for (int e = 0; e < 2; ++e) {
            int jl = lane + e * 64;
            unsigned short hv = T[ql][jl];
            if (jl < jm) {
                if (q > 0)
                    out[(size_t)(q - 1) * S_LEN + (m0 + jl + q + 1)] = hv;
            } else {
                out[(size_t)q * S_LEN + (m0 + jl - 2047 + q)] = hv;
            }
        }
    }
}

// ---------------------------------------------------------------------------
// Flash attention, Round-15: q-split + cooperative bulk LDS staging.
// Block = 64 q-rows (4 waves x 16 q each); all waves march k-tiles 0..15
// (128 k each).  Per tile the block stages:
//   Kbuf 16KB: K[k_local 0..128][d 0..64], row 128B = 8 chunks16,
//              LDS[row][c] = K[row][c ^ (row&7)]  (src pre-swizzled)
//   Vbuf 16KB: V[d 0..64][k_local 0..128], row 256B = 16 chunks16,
//              LDS[d][c] = V[d][c ^ (d&15)]
//   PosB 4KB/wave: this wave's 16 q-rows' Pshift[q][k0..k0+128) windows
//              (chunk layout identical to r14; extraction code unchanged)
// via 12 global_load_lds per wave (4 K + 4 V + 4 Pos), all in flight at
// once; __syncthreads() at tile top drains vmcnt and publishes the stage.
// P -> PV A-fragment via in-register shfl transpose (no Sp LDS buffer).
// Each wave owns its 16 q-rows end-to-end -> no cross-wave merge.
// LDS 48KB -> 2 blocks/CU; grid = chunk_heads * 32.
// ---------------------------------------------------------------------------
__global__ __launch_bounds__(256, 2)
void attn_fused(const unsigned short* __restrict__ qu,
                const unsigned short* __restrict__ kdat,
                const unsigned short* __restrict__ vtg,
                const unsigned short* __restrict__ pp,
                unsigned short* __restrict__ ctx, int head_base)
{
    __shared__ __align__(16) unsigned short Kbuf[8192];     // 16 KB
    __shared__ __align__(16) unsigned short Vbuf[8192];     // 16 KB
    __shared__ __align__(16) unsigned short PosB[4][2048];  // 4 KB/wave

    const int t = threadIdx.x;
    const int wave = t >> 6, lane = t & 63;
    const int quad = lane >> 4, l16 = lane & 15;
    const int z = blockIdx.x >> 5, qt = blockIdx.x & 31;
    const int g = head_base + z;
    const int q0w = qt * 64 + wave * 16;     // this wave's q-row base
    const int q = q0w + l16;                 // this lane's q row

    const unsigned short* QU = qu   + (size_t)g * HEAD_ELEMS;
    const unsigned short* Kg = kdat + (size_t)g * HEAD_ELEMS;
    const unsigned short* Vg = vtg  + (size_t)g * HEAD_ELEMS;
    const unsigned short* Pg = pp   + (size_t)z * SS;
    unsigned short* pbuf = &PosB[wave][0];
    const unsigned short* gdma = Pg + (size_t)q * S_LEN;    // row base, 4KB-aligned

    // staging lane roles (constant per thread)
    const int krow_l = lane >> 3, kch_l = lane & 7;    // within 8-row K group
    const int vrow_l = lane >> 4, vch_l = lane & 15;   // within 4-row V group

#define STAGE(TT)                                                             \
    {                                                                         \
        const int k0s = (TT) * 128;                                           \
        _Pragma("unroll")                                                     \
        for (int jj = 0; jj < 4; ++jj) {                                      \
            const int j = wave * 4 + jj;                                      \
            /* K: inst j covers rows j*8..j*8+8; lane -> row j*8+l/8, chunk l%8 */ \
            {                                                                 \
                int kr = j * 8 + krow_l;                                      \
                int kc = kch_l ^ (kr & 7);                                    \
                __builtin_amdgcn_global_load_lds(                             \
                    (const __attribute__((address_space(1))) unsigned int*)   \
                        (Kg + (size_t)(k0s + kr) * DHD + kc * 8),             \
                    (__attribute__((address_space(3))) unsigned int*)         \
                        (Kbuf + j * 512), 16, 0, 0);                          \
            }                                                                 \
            /* V: inst j covers d-rows j*4..j*4+4; lane -> row j*4+l/16, chunk l%16 */ \
            {                                                                 \
                int vr = j * 4 + vrow_l;                                      \
                int vc = vch_l ^ (vr & 15);                                   \
                __builtin_amdgcn_global_load_lds(                             \
                    (const __attribute__((address_space(1))) unsigned int*)   \
                        (Vg + (size_t)vr * S_LEN + k0s + vc * 8),             \
                    (__attribute__((address_space(3))) unsigned int*)         \
                        (Vbuf + j * 512), 16, 0, 0);                          \
            }                                                                 \
            /* Pos: this wave's 16 q-rows, chunk jj*4+quad of 256B window */  \
            __builtin_amdgcn_global_load_lds(                                 \
                (const __attribute__((address_space(1))) unsigned int*)       \
                    (gdma + k0s + (jj * 4 + quad) * 8),                       \
                (__attribute__((address_space(3))) unsigned int*)             \
                    (pbuf + jj * 512), 16, 0, 0);                             \
        }                                                                     \
    }

    STAGE(0)

    const v8s bq0 = *(const v8s*)(QU + (size_t)q * DHD + quad * 8);
    const v8s bq1 = *(const v8s*)(QU + (size_t)q * DHD + 32 + quad * 8);

    float m_run = -1e30f, l_run = 0.f;
    v4f accv[4];
#pragma unroll
    for (int r = 0; r < 4; ++r) accv[r] = (v4f){0.f, 0.f, 0.f, 0.f};
    const float scale = 0.04419417382415922f;

    for (int tt = 0; tt < 16; ++tt) {
        const int k0 = tt * 128;

        __syncthreads();   // drains own stage (vmcnt) + publishes all waves'

        // QK^T from Kbuf (swizzled ds_read_b128)
        v4f sacc[8];
#pragma unroll
        for (int nt = 0; nt < 8; ++nt) {
            int r = nt * 16 + l16;
            const unsigned short* kl = Kbuf + r * 64;
            v8s a0 = *(const v8s*)(kl + ((quad ^ (r & 7)) * 8));
            v8s a1 = *(const v8s*)(kl + (((4 + quad) ^ (r & 7)) * 8));
            v4f c = (v4f){0.f, 0.f, 0.f, 0.f};
            c = __builtin_amdgcn_mfma_f32_16x16x32_f16(a0, bq0, c, 0, 0, 0);
            c = __builtin_amdgcn_mfma_f32_16x16x32_f16(a1, bq1, c, 0, 0, 0);
            sacc[nt] = c;
        }

        // add pre-shifted pos from PosB (layout identical to r14) + scale
        float tm = -1e30f;
#pragma unroll
        for (int nt = 0; nt < 8; ++nt) {
            int kb = k0 + nt * 16 + quad * 4;
            int cc = nt * 2 + (quad >> 1);
            uint2 w = *(const uint2*)((const char*)pbuf +
                         (cc >> 2) * 1024 + (cc & 3) * 256 + l16 * 16 + (quad & 1) * 8);
            unsigned short h_[4] = { (unsigned short)(w.x & 0xffff),
                                     (unsigned short)(w.x >> 16),
                                     (unsigned short)(w.y & 0xffff),
                                     (unsigned short)(w.y >> 16) };
#pragma unroll
            for (int reg = 0; reg < 4; ++reg) {
                int k = kb + reg;
                float pv = (k == q + 1) ? 0.f : h2f(h_[reg]);
                sacc[nt][reg] = (sacc[nt][reg] + pv) * scale;
                tm = fmaxf(tm, sacc[nt][reg]);
            }
        }

        // online softmax (per-lane q = l16; reduce across the 4 quads)
        tm = fmaxf(tm, __shfl_xor(tm, 16));
        tm = fmaxf(tm, __shfl_xor(tm, 32));
        float mn = fmaxf(m_run, tm);
        float al = __expf(m_run - mn);
        float rs = 0.f;
#pragma unroll
        for (int nt = 0; nt < 8; ++nt)
#pragma unroll
            for (int reg = 0; reg < 4; ++reg) {
                sacc[nt][reg] = __expf(sacc[nt][reg] - mn);
                rs += sacc[nt][reg];
            }
        rs += __shfl_xor(rs, 16);
        rs += __shfl_xor(rs, 32);
        l_run = l_run * al + rs;
        m_run = mn;

        float alr[4];
#pragma unroll
        for (int reg = 0; reg < 4; ++reg) alr[reg] = __shfl(al, quad * 4 + reg);
#pragma unroll
        for (int ntd = 0; ntd < 4; ++ntd)
#pragma unroll
            for (int reg = 0; reg < 4; ++reg) accv[ntd][reg] *= alr[reg];

        // pack P to fp16 word-pairs (per nt): pk[nt][0] = regs 0,1; [1] = 2,3
        unsigned pk[8][2];
#pragma unroll
        for (int nt = 0; nt < 8; ++nt) {
            pk[nt][0] = pkh(sacc[nt][0], sacc[nt][1]);
            pk[nt][1] = pkh(sacc[nt][2], sacc[nt][3]);
        }

        // PV: A-fragment via shfl transpose, B from Vbuf (swizzled)
        const int sA = l16 + ((quad & 1) * 32);
        const bool hi = (quad >= 2);
#pragma unroll
        for (int c4 = 0; c4 < 4; ++c4) {
            unsigned a0A = __shfl((int)pk[c4 * 2][0], sA);
            unsigned a1A = __shfl((int)pk[c4 * 2][1], sA);
            unsigned a0B = __shfl((int)pk[c4 * 2][0], sA + 16);
            unsigned a1B = __shfl((int)pk[c4 * 2][1], sA + 16);
            unsigned b0A = __shfl((int)pk[c4 * 2 + 1][0], sA);
            unsigned b1A = __shfl((int)pk[c4 * 2 + 1][1], sA);
            unsigned b0B = __shfl((int)pk[c4 * 2 + 1][0], sA + 16);
            unsigned b1B = __shfl((int)pk[c4 * 2 + 1][1], sA + 16);
            union { unsigned u[4]; v8s v; } apu;
            apu.u[0] = hi ? b0A : a0A;
            apu.u[1] = hi ? b1A : a1A;
            apu.u[2] = hi ? b0B : a0B;
            apu.u[3] = hi ? b1B : a1B;
#pragma unroll
            for (int ntd = 0; ntd < 4; ++ntd) {
                int d = ntd * 16 + l16;
                v8s bv8 = *(const v8s*)(Vbuf + d * 128 +
                                        (((c4 * 4 + quad) ^ (d & 15)) * 8));
                accv[ntd] = __builtin_amdgcn_mfma_f32_16x16x32_f16(apu.v, bv8, accv[ntd], 0, 0, 0);
            }
        }

        __syncthreads();   // all waves done reading Kbuf/Vbuf
        if (tt < 15) STAGE(tt + 1)
    }
#undef STAGE

    // epilogue: each wave owns its 16 q-rows completely.
    // accv[ntd][reg] = out[q = q0w + quad*4+reg][d = ntd*16 + l16] (unnormalized)
    const int bb = g >> 3, h = g & 7;
    float inv[4];
#pragma unroll
    for (int reg = 0; reg < 4; ++reg)
        inv[reg] = 1.f / __shfl(l_run, quad * 4 + reg);
#pragma unroll
    for (int ntd = 0; ntd < 4; ++ntd)
#pragma unroll
        for (int reg = 0; reg < 4; ++reg) {
            int qq = q0w + quad * 4 + reg;
            ctx[((size_t)(bb * S_LEN + qq)) * DM + h * DHD + ntd * 16 + l16] =
                f2h(accv[ntd][reg] * inv[reg]);
        }
}

// ---------------------------------------------------------------------------
// out_mfma: out(fp32)[s][n] = ctx(fp16) @ Wo + bo.  SWAPPED: C[n][s] ->
// float4 stores.  grid (32, 4): x = s-tile(128), y = n-tile(128).
// ---------------------------------------------------------------------------
__global__ __launch_bounds__(256)
void out_mfma(const float* __restrict__ bo, const char* __restrict__ wsb,
              float* __restrict__ out)
{
    const int t = threadIdx.x;
    const int wave = t >> 6, lane = t & 63;
    const int quad = lane >> 4, l16 = lane & 15;
    const int wm = wave >> 1, wn = wave & 1;
    const int n0 = blockIdx.y * 128 + wm * 64;
    const int s0 = blockIdx.x * 128 + wn * 64;
    const unsigned short* A = (const unsigned short*)(wsb + BY_WT) + (size_t)4 * WT_MAT_HALFS;
    const unsigned short* B = (const unsigned short*)(wsb + BY_CTX);

    v4f acc[4][4];
#pragma unroll
    for (int i = 0; i < 4; ++i)
#pragma unroll
        for (int j = 0; j < 4; ++j) acc[i][j] = (v4f){0.f, 0.f, 0.f, 0.f};

    for (int kk = 0; kk < 16; ++kk) {
        v8s af[4], bf[4];
#pragma unroll
        for (int i = 0; i < 4; ++i) {
            af[i] = *(const v8s*)(A + (size_t)(n0 + i * 16 + l16) * 512 + kk * 32 + quad * 8);
            bf[i] = *(const v8s*)(B + (size_t)(s0 + i * 16 + l16) * 512 + kk * 32 + quad * 8);
        }
#pragma unroll
        for (int i = 0; i < 4; ++i)
#pragma unroll
            for (int j = 0; j < 4; ++j)
                acc[i][j] = __builtin_amdgcn_mfma_f32_16x16x32_f16(af[i], bf[j], acc[i][j], 0, 0, 0);
    }

#pragma unroll
    for (int i = 0; i < 4; ++i) {
        int nb = n0 + i * 16 + quad * 4;
        float4 b4 = *(const float4*)(bo + nb);
#pragma unroll
        for (int j = 0; j < 4; ++j) {
            int s = s0 + j * 16 + l16;
            *(float4*)(out + (size_t)s * DM + nb) =
                make_float4(acc[i][j][0] + b4.x, acc[i][j][1] + b4.y,
                            acc[i][j][2] + b4.z, acc[i][j][3] + b4.w);
        }
    }
}

// Fallback when ws_size is insufficient: clean mismatch instead of OOB writes.
__global__ void zero_fill(float* __restrict__ p, int n)
{
    int i = blockIdx.x * 256 + threadIdx.x;
    if (i < n) p[i] = 0.f;
}

// ---------------------------------------------------------------------------
extern "C" void kernel_launch(void* const* d_in, const int* in_sizes, int n_in,
                              void* d_out, int out_size, void* d_ws, size_t ws_size,
                              hipStream_t stream)
{
    const float* x   = (const float*)d_in[0];
    const float* pos = (const float*)d_in[1];
    const float* Wq  = (const float*)d_in[2];
    const float* bq  = (const float*)d_in[3];
    const float* Wk  = (const float*)d_in[4];
    const float* bk  = (const float*)d_in[5];
    const float* Wv  = (const float*)d_in[6];
    const float* bv  = (const float*)d_in[7];
    const float* Wp  = (const float*)d_in[8];
    const float* u   = (const float*)d_in[9];
    const float* v   = (const float*)d_in[10];
    const float* Wo  = (const float*)d_in[11];
    const float* bo  = (const float*)d_in[12];
    char* wsb  = (char*)d_ws;
    float* out = (float*)d_out;

    // Workspace guard: need BY_PP + >=1 head of Pshift + slack.
    if (ws_size < (size_t)BY_PP + PP_HEAD_BYTES + 4096) {
        zero_fill<<<(out_size + 255) / 256, 256, 0, stream>>>(out, out_size);
        return;
    }

    // 1. dtype prep
    conv_inputs<<<dim3(2048, 1, 2), 256, 0, stream>>>(x, pos, wsb);
    conv_wt<<<dim3(8, 8, 5), 256, 0, stream>>>(Wq, Wk, Wv, Wp, Wo, wsb);

    // 2. projections (fp16 MFMA)
    proj_mfma<<<dim3(32, 4, 4), 256, 0, stream>>>(bq, bk, bv, u, v, wsb);

    // 3. attention in head-chunks sized to workspace.
    int c = (int)((ws_size - 4096 - (size_t)BY_PP) / (size_t)PP_HEAD_BYTES);
    if (c < 1) c = 1;
    if (c > CHUNK_CAP) c = CHUNK_CAP;

    for (int g0 = 0; g0 < NBH; g0 += c) {
        int cc = (NBH - g0 < c) ? (NBH - g0) : c;
        pos_gemm<<<dim3(16, 16, cc), 256, 0, stream>>>(
            (const unsigned short*)(wsb + BY_QV),
            (const unsigned short*)(wsb + BY_PB),
            (unsigned short*)(wsb + BY_PP), g0);
        attn_fused<<<dim3(cc * 32), 256, 0, stream>>>(
            (const unsigned short*)(wsb + BY_QU),
            (const unsigned short*)(wsb + BY_K),
            (const unsigned short*)(wsb + BY_VT),
            (const unsigned short*)(wsb + BY_PP),
            (unsigned short*)(wsb + BY_CTX), g0);
    }

    // 4. output projection (fp16 MFMA, fp32 out)
    out_mfma<<<dim3(32, 4), 256, 0, stream>>>(bo, wsb, out);
}